// Round 1
// baseline (1063.736 us; speedup 1.0000x reference)
//
#include <hip/hip_runtime.h>
#include <math.h>

#define HID 128

// ---------------------------------------------------------------------------
// dtype detection: reference declares int64 indices, harness doc says int32.
// Detect on-device: for int64 (values < 2^31), odd int32 words are all zero.
__global__ void detect_flags(const int* __restrict__ ei, const int* __restrict__ gi,
                             int* __restrict__ flags, int n_nodes) {
  if (blockIdx.x == 0 && threadIdx.x == 0) {
    int nz = 0;
    for (int i = 1; i < 64; i += 2) nz |= ei[i];       // src[1],src[3].. or high words
    flags[0] = (nz == 0) ? 1 : 0;                       // 1 => edge_index is int64
    // graph_indicator sorted 0..63; int32 view last element: int32 case -> 63,
    // int64 case -> high word == 0.
    flags[1] = (gi[n_nodes - 1] == 0) ? 1 : 0;          // 1 => graph_indicator is int64
  }
}

// ---------------------------------------------------------------------------
// Load edges into int32 src/dst arrays + dst histogram (for CSR build).
__global__ void load_edges_hist(const void* __restrict__ ei_raw, const int* __restrict__ flags,
                                int* __restrict__ src, int* __restrict__ dst,
                                int* __restrict__ counts, int E) {
  int e = blockIdx.x * blockDim.x + threadIdx.x;
  if (e >= E) return;
  int s, d;
  if (flags[0]) {
    const long long* p = (const long long*)ei_raw;
    s = (int)p[e]; d = (int)p[E + e];
  } else {
    const int* p = (const int*)ei_raw;
    s = p[e]; d = p[E + e];
  }
  src[e] = s; dst[e] = d;
  atomicAdd(&counts[d], 1);
}

// ---------------------------------------------------------------------------
// Single-block hierarchical exclusive scan of counts[n] -> row_ptr[n+1], cursor[n].
__global__ __launch_bounds__(1024) void scan_counts(const int* __restrict__ counts,
                                                    int* __restrict__ row_ptr,
                                                    int* __restrict__ cursor, int n) {
  __shared__ int wsum[16];
  __shared__ int carry_s;
  int t = threadIdx.x, lane = t & 63, w = t >> 6;
  if (t == 0) carry_s = 0;
  __syncthreads();
  for (int base = 0; base < n; base += 1024) {
    int i = base + t;
    int v = (i < n) ? counts[i] : 0;
    int incl = v;
#pragma unroll
    for (int d = 1; d < 64; d <<= 1) {
      int x = __shfl_up(incl, (unsigned)d, 64);
      if (lane >= d) incl += x;
    }
    if (lane == 63) wsum[w] = incl;
    __syncthreads();
    int wbase = carry_s;
    for (int j = 0; j < w; j++) wbase += wsum[j];
    if (i < n) {
      int excl = wbase + incl - v;
      row_ptr[i] = excl;
      cursor[i] = excl;
    }
    __syncthreads();
    if (t == 0) {
      int tot = 0;
      for (int j = 0; j < 16; j++) tot += wsum[j];
      carry_s += tot;
    }
    __syncthreads();
  }
  if (t == 0) row_ptr[n] = carry_s;
}

// ---------------------------------------------------------------------------
// Scatter edges into CSR slots (order within a node irrelevant: sum is commutative).
__global__ void scatter_edges(const int* __restrict__ src, const int* __restrict__ dst,
                              const float* __restrict__ ew, int* __restrict__ cursor,
                              int* __restrict__ csr_src, float* __restrict__ csr_w, int E) {
  int e = blockIdx.x * blockDim.x + threadIdx.x;
  if (e >= E) return;
  int d = dst[e];
  int pos = atomicAdd(&cursor[d], 1);
  csr_src[pos] = src[e];
  csr_w[pos] = ew[e];
}

// ---------------------------------------------------------------------------
// C[n x 128] = A[n x 128] @ W[128 x 128].  One output column per thread, W column
// held in 128 VGPRs, A tile (32 rows) staged in LDS and broadcast.
__global__ __launch_bounds__(128) void gemm128(const float* __restrict__ A,
                                               const float* __restrict__ W,
                                               float* __restrict__ C, int n) {
  __shared__ float4 a_lds[32 * 32];  // 32 rows x 128 cols
  int c = threadIdx.x;
  int r0 = blockIdx.x * 32;
  float w[128];
#pragma unroll
  for (int k = 0; k < 128; k++) w[k] = W[k * 128 + c];  // coalesced across threads

  const float4* A4 = (const float4*)A;
  for (int idx = c; idx < 32 * 32; idx += 128) {
    int r = idx >> 5;
    float4 v;
    if (r0 + r < n) v = A4[(size_t)(r0 + r) * 32 + (idx & 31)];
    else { v.x = v.y = v.z = v.w = 0.f; }
    a_lds[idx] = v;
  }
  __syncthreads();

  int rmax = n - r0; if (rmax > 32) rmax = 32;
  for (int r = 0; r < rmax; r++) {
    const float4* arow = &a_lds[r * 32];
    float acc0 = 0.f, acc1 = 0.f, acc2 = 0.f, acc3 = 0.f;
#pragma unroll
    for (int k4 = 0; k4 < 32; k4 += 4) {
      float4 a0 = arow[k4 + 0];
      float4 a1 = arow[k4 + 1];
      float4 a2 = arow[k4 + 2];
      float4 a3 = arow[k4 + 3];
      int kb = k4 * 4;
      acc0 += a0.x * w[kb + 0]  + a0.y * w[kb + 1]  + a0.z * w[kb + 2]  + a0.w * w[kb + 3];
      acc1 += a1.x * w[kb + 4]  + a1.y * w[kb + 5]  + a1.z * w[kb + 6]  + a1.w * w[kb + 7];
      acc2 += a2.x * w[kb + 8]  + a2.y * w[kb + 9]  + a2.z * w[kb + 10] + a2.w * w[kb + 11];
      acc3 += a3.x * w[kb + 12] + a3.y * w[kb + 13] + a3.z * w[kb + 14] + a3.w * w[kb + 15];
    }
    C[(size_t)(r0 + r) * 128 + c] = acc0 + acc1 + acc2 + acc3;
  }
}

// ---------------------------------------------------------------------------
// g[node][:] = relu(bias + sum_{e in CSR[node]} w_e * support[src_e][:])
// thread = (node, 4-dim group); float4 gather, no atomics.
__global__ void aggregate(const float* __restrict__ support, const int* __restrict__ row_ptr,
                          const int* __restrict__ csr_src, const float* __restrict__ csr_w,
                          const float* __restrict__ bias, float* __restrict__ out, int n) {
  int gid = blockIdx.x * blockDim.x + threadIdx.x;
  int node = gid >> 5, q = gid & 31;
  if (node >= n) return;
  int beg = row_ptr[node], end = row_ptr[node + 1];
  float4 acc; acc.x = acc.y = acc.z = acc.w = 0.f;
  const float4* s4 = (const float4*)support;
  for (int i = beg; i < end; i++) {
    int s = csr_src[i];
    float wt = csr_w[i];
    float4 v = s4[(size_t)s * 32 + q];
    acc.x += wt * v.x; acc.y += wt * v.y; acc.z += wt * v.z; acc.w += wt * v.w;
  }
  float4 b = ((const float4*)bias)[q];
  acc.x = fmaxf(acc.x + b.x, 0.f);
  acc.y = fmaxf(acc.y + b.y, 0.f);
  acc.z = fmaxf(acc.z + b.z, 0.f);
  acc.w = fmaxf(acc.w + b.w, 0.f);
  ((float4*)out)[(size_t)node * 32 + q] = acc;
}

// ---------------------------------------------------------------------------
// s_pre[n] = h[n] . wa  with h = concat(g1,g2,g3). One wave per node.
__global__ void att_score(const float* __restrict__ g1, const float* __restrict__ g2,
                          const float* __restrict__ g3, const float* __restrict__ wa,
                          float* __restrict__ s_pre, int n) {
  int wid = (blockIdx.x * blockDim.x + threadIdx.x) >> 6;
  int lane = threadIdx.x & 63;
  if (wid >= n) return;
  size_t base = (size_t)wid * 128;
  float acc = g1[base + lane] * wa[lane]       + g1[base + lane + 64] * wa[lane + 64]
            + g2[base + lane] * wa[128 + lane] + g2[base + lane + 64] * wa[192 + lane]
            + g3[base + lane] * wa[256 + lane] + g3[base + lane + 64] * wa[320 + lane];
#pragma unroll
  for (int off = 32; off > 0; off >>= 1) acc += __shfl_down(acc, (unsigned)off, 64);
  if (lane == 0) s_pre[wid] = acc;
}

// ---------------------------------------------------------------------------
// score[n] = tanh(ba + sum_e w_e * s_pre[src_e]). One thread per node.
__global__ void att_aggregate(const float* __restrict__ s_pre, const int* __restrict__ row_ptr,
                              const int* __restrict__ csr_src, const float* __restrict__ csr_w,
                              const float* __restrict__ ba, float* __restrict__ score, int n) {
  int node = blockIdx.x * blockDim.x + threadIdx.x;
  if (node >= n) return;
  int beg = row_ptr[node], end = row_ptr[node + 1];
  float acc = 0.f;
  for (int i = beg; i < end; i++) acc += csr_w[i] * s_pre[csr_src[i]];
  score[node] = tanhf(acc + ba[0]);
}

// ---------------------------------------------------------------------------
// Per-graph node ranges via binary search on sorted graph_indicator.
__global__ void graph_bounds(const void* __restrict__ gi_raw, const int* __restrict__ flags,
                             int* __restrict__ gstart, int n, int ngraphs) {
  int g = threadIdx.x;
  if (g > ngraphs) return;
  if (g == ngraphs) { gstart[g] = n; return; }
  bool is64 = flags[1] != 0;
  const long long* g64 = (const long long*)gi_raw;
  const int* g32 = (const int*)gi_raw;
  int lo = 0, hi = n;
  while (lo < hi) {
    int mid = (lo + hi) >> 1;
    long long v = is64 ? g64[mid] : (long long)g32[mid];
    if (v < (long long)g) lo = mid + 1; else hi = mid;
  }
  gstart[g] = lo;
}

// ---------------------------------------------------------------------------
// pooled[g] = [avg(h*score), max(h*score)] over the graph's node range.
// One block per graph, 384 threads (one per h-dim).
__global__ __launch_bounds__(384) void pool_reduce(const float* __restrict__ g1,
                                                   const float* __restrict__ g2,
                                                   const float* __restrict__ g3,
                                                   const float* __restrict__ score,
                                                   const int* __restrict__ gstart,
                                                   float* __restrict__ pooled) {
  int g = blockIdx.x;
  int d = threadIdx.x;           // 0..383
  int seg = d >> 7, dd = d & 127;
  const float* gp = (seg == 0) ? g1 : ((seg == 1) ? g2 : g3);
  int s = gstart[g], e = gstart[g + 1];
  float sum = 0.f, mx = -3.402823466e38f;
  for (int node = s; node < e; node++) {
    float sc = score[node];
    float v = gp[(size_t)node * 128 + dd] * sc;
    sum += v;
    mx = fmaxf(mx, v);
  }
  float cnt = (float)(e - s);
  pooled[(size_t)g * 768 + d] = sum / fmaxf(cnt, 1.0f);
  pooled[(size_t)g * 768 + 384 + d] = mx;
}

// ---------------------------------------------------------------------------
// out = relu(pooled @ Wf + bf).  [64,768]@[768,128]; one block per graph row.
__global__ __launch_bounds__(128) void final_gemm(const float* __restrict__ pooled,
                                                  const float* __restrict__ Wf,
                                                  const float* __restrict__ bf,
                                                  float* __restrict__ out) {
  int g = blockIdx.x;
  int c = threadIdx.x;
  __shared__ float row[768];
  for (int i = c; i < 768; i += 128) row[i] = pooled[(size_t)g * 768 + i];
  __syncthreads();
  float acc = bf[c];
#pragma unroll 8
  for (int k = 0; k < 768; k++) acc += row[k] * Wf[k * 128 + c];
  out[(size_t)g * 128 + c] = fmaxf(acc, 0.f);
}

// ---------------------------------------------------------------------------
extern "C" void kernel_launch(void* const* d_in, const int* in_sizes, int n_in,
                              void* d_out, int out_size, void* d_ws, size_t ws_size,
                              hipStream_t stream) {
  const void* ei_raw = d_in[0];
  const float* ew    = (const float*)d_in[1];
  const float* X     = (const float*)d_in[2];
  const void* gi_raw = d_in[3];
  const float* W1 = (const float*)d_in[4];  const float* b1 = (const float*)d_in[5];
  const float* W2 = (const float*)d_in[6];  const float* b2 = (const float*)d_in[7];
  const float* W3 = (const float*)d_in[8];  const float* b3 = (const float*)d_in[9];
  const float* wa = (const float*)d_in[10]; const float* ba = (const float*)d_in[11];
  const float* Wf = (const float*)d_in[12]; const float* bf = (const float*)d_in[13];
  float* out = (float*)d_out;

  const int E = in_sizes[1];            // 800000
  const int N = in_sizes[2] / 128;      // 50000
  const int G = out_size / 128;         // 64

  char* ws = (char*)d_ws;
  size_t off = 0;
  auto take = [&](size_t bytes) {
    char* p = ws + off;
    off = (off + bytes + 255) & ~(size_t)255;
    return p;
  };
  int*   flags   = (int*)take(16);
  int*   srcA    = (int*)take((size_t)E * 4);
  int*   dstA    = (int*)take((size_t)E * 4);
  int*   counts  = (int*)take((size_t)N * 4);
  int*   row_ptr = (int*)take((size_t)(N + 1) * 4);
  int*   cursor  = (int*)take((size_t)N * 4);
  int*   csr_src = (int*)take((size_t)E * 4);
  float* csr_w   = (float*)take((size_t)E * 4);
  float* support = (float*)take((size_t)N * 128 * 4);
  float* g1      = (float*)take((size_t)N * 128 * 4);
  float* g2      = (float*)take((size_t)N * 128 * 4);
  float* g3      = (float*)take((size_t)N * 128 * 4);
  float* s_pre   = (float*)take((size_t)N * 4);
  float* score   = (float*)take((size_t)N * 4);
  int*   gstart  = (int*)take((size_t)(G + 1) * 4);
  float* pooled  = (float*)take((size_t)G * 768 * 4);
  if (off > ws_size) return;  // fail loudly (output stays zeroed) rather than corrupt

  hipMemsetAsync(counts, 0, (size_t)N * 4, stream);
  detect_flags<<<1, 64, 0, stream>>>((const int*)ei_raw, (const int*)gi_raw, flags, N);
  load_edges_hist<<<(E + 255) / 256, 256, 0, stream>>>(ei_raw, flags, srcA, dstA, counts, E);
  scan_counts<<<1, 1024, 0, stream>>>(counts, row_ptr, cursor, N);
  scatter_edges<<<(E + 255) / 256, 256, 0, stream>>>(srcA, dstA, ew, cursor, csr_src, csr_w, E);

  // layer 1
  gemm128<<<(N + 31) / 32, 128, 0, stream>>>(X, W1, support, N);
  aggregate<<<((size_t)N * 32 + 255) / 256, 256, 0, stream>>>(support, row_ptr, csr_src, csr_w, b1, g1, N);
  // layer 2
  gemm128<<<(N + 31) / 32, 128, 0, stream>>>(g1, W2, support, N);
  aggregate<<<((size_t)N * 32 + 255) / 256, 256, 0, stream>>>(support, row_ptr, csr_src, csr_w, b2, g2, N);
  // layer 3
  gemm128<<<(N + 31) / 32, 128, 0, stream>>>(g2, W3, support, N);
  aggregate<<<((size_t)N * 32 + 255) / 256, 256, 0, stream>>>(support, row_ptr, csr_src, csr_w, b3, g3, N);

  // attention score
  att_score<<<(N + 3) / 4, 256, 0, stream>>>(g1, g2, g3, wa, s_pre, N);
  att_aggregate<<<(N + 255) / 256, 256, 0, stream>>>(s_pre, row_ptr, csr_src, csr_w, ba, score, N);

  // pooling + readout
  graph_bounds<<<1, 128, 0, stream>>>(gi_raw, flags, gstart, N, G);
  pool_reduce<<<G, 384, 0, stream>>>(g1, g2, g3, score, gstart, pooled);
  final_gemm<<<G, 128, 0, stream>>>(pooled, Wf, bf, out);
}

// Round 2
// 799.276 us; speedup vs baseline: 1.3309x; 1.3309x over previous
//
#include <hip/hip_runtime.h>
#include <math.h>

#define HID 128
#define POOL_SEG 16
#define SCAN_TPB 1024
#define SCAN_ELEMS 4096   // SCAN_TPB * 4

// ---------------------------------------------------------------------------
// dtype detection: reference declares int64 indices, harness doc says int32.
// Detect on-device: for int64 (values < 2^31), odd int32 words are all zero.
__global__ void detect_flags(const int* __restrict__ ei, const int* __restrict__ gi,
                             int* __restrict__ flags, int n_nodes) {
  if (blockIdx.x == 0 && threadIdx.x == 0) {
    int nz = 0;
    for (int i = 1; i < 64; i += 2) nz |= ei[i];       // src[1],src[3].. or high words
    flags[0] = (nz == 0) ? 1 : 0;                       // 1 => edge_index is int64
    flags[1] = (gi[n_nodes - 1] == 0) ? 1 : 0;          // 1 => graph_indicator is int64
  }
}

// ---------------------------------------------------------------------------
// Load edges into int32 src/dst arrays + dst histogram (for CSR build).
__global__ void load_edges_hist(const void* __restrict__ ei_raw, const int* __restrict__ flags,
                                int* __restrict__ src, int* __restrict__ dst,
                                int* __restrict__ counts, int E) {
  int e = blockIdx.x * blockDim.x + threadIdx.x;
  if (e >= E) return;
  int s, d;
  if (flags[0]) {
    const long long* p = (const long long*)ei_raw;
    s = (int)p[e]; d = (int)p[E + e];
  } else {
    const int* p = (const int*)ei_raw;
    s = p[e]; d = p[E + e];
  }
  src[e] = s; dst[e] = d;
  atomicAdd(&counts[d], 1);
}

// ---------------------------------------------------------------------------
// 3-phase exclusive scan of counts[n] -> row_ptr[0..n], cursor[n].
// Phase 1: per-block (4096 elems) local exclusive scan + block total.
__global__ __launch_bounds__(SCAN_TPB) void scan_partial(const int* __restrict__ counts,
                                                         int* __restrict__ row_ptr,
                                                         int* __restrict__ partials, int n) {
  __shared__ int wsum[16];
  int b = blockIdx.x, t = threadIdx.x;
  int base = b * SCAN_ELEMS + t * 4;
  int4 v; v.x = v.y = v.z = v.w = 0;
  if (base + 3 < n) v = *(const int4*)(counts + base);
  else {
    if (base + 0 < n) v.x = counts[base + 0];
    if (base + 1 < n) v.y = counts[base + 1];
    if (base + 2 < n) v.z = counts[base + 2];
  }
  int s01 = v.x + v.y, s012 = s01 + v.z, tot4 = s012 + v.w;
  int lane = t & 63, w = t >> 6;
  int incl = tot4;
#pragma unroll
  for (int d = 1; d < 64; d <<= 1) {
    int x = __shfl_up(incl, (unsigned)d, 64);
    if (lane >= d) incl += x;
  }
  if (lane == 63) wsum[w] = incl;
  __syncthreads();
  int wbase = 0;
  for (int j = 0; j < w; j++) wbase += wsum[j];
  int excl = wbase + incl - tot4;
  int4 o; o.x = excl; o.y = excl + v.x; o.z = excl + s01; o.w = excl + s012;
  if (base + 3 < n) *(int4*)(row_ptr + base) = o;
  else {
    if (base + 0 < n) row_ptr[base + 0] = o.x;
    if (base + 1 < n) row_ptr[base + 1] = o.y;
    if (base + 2 < n) row_ptr[base + 2] = o.z;
  }
  if (t == SCAN_TPB - 1) partials[b] = excl + tot4;   // block total
}

// Phase 2: single wave scans the (<=64) block totals, exclusive, + grand total.
__global__ void scan_tops(int* __restrict__ partials, int B) {
  int t = threadIdx.x;
  int v = (t < B) ? partials[t] : 0;
  int incl = v;
#pragma unroll
  for (int d = 1; d < 64; d <<= 1) {
    int x = __shfl_up(incl, (unsigned)d, 64);
    if (t >= d) incl += x;
  }
  if (t < B) partials[t] = incl - v;     // exclusive
  if (t == 63) partials[B] = incl;       // grand total
}

// Phase 3: add block offsets; duplicate into cursor; write row_ptr[n].
__global__ void scan_add(int* __restrict__ row_ptr, int* __restrict__ cursor,
                         const int* __restrict__ partials, int n, int B) {
  int i = blockIdx.x * blockDim.x + threadIdx.x;
  if (i < n) {
    int v = row_ptr[i] + partials[i >> 12];
    row_ptr[i] = v;
    cursor[i] = v;
  }
  if (i == 0) row_ptr[n] = partials[B];
}

// ---------------------------------------------------------------------------
// Scatter edges into CSR slots (order within a node irrelevant: sum is commutative).
__global__ void scatter_edges(const int* __restrict__ src, const int* __restrict__ dst,
                              const float* __restrict__ ew, int* __restrict__ cursor,
                              int* __restrict__ csr_src, float* __restrict__ csr_w, int E) {
  int e = blockIdx.x * blockDim.x + threadIdx.x;
  if (e >= E) return;
  int d = dst[e];
  int pos = atomicAdd(&cursor[d], 1);
  csr_src[pos] = src[e];
  csr_w[pos] = ew[e];
}

// ---------------------------------------------------------------------------
// C[n x 128] = A[n x 128] @ W[128 x 128].  One output column per thread, W column
// held in 128 VGPRs, A tile (32 rows) staged in LDS and broadcast.
__global__ __launch_bounds__(128) void gemm128(const float* __restrict__ A,
                                               const float* __restrict__ W,
                                               float* __restrict__ C, int n) {
  __shared__ float4 a_lds[32 * 32];  // 32 rows x 128 cols
  int c = threadIdx.x;
  int r0 = blockIdx.x * 32;
  float w[128];
#pragma unroll
  for (int k = 0; k < 128; k++) w[k] = W[k * 128 + c];  // coalesced across threads

  const float4* A4 = (const float4*)A;
  for (int idx = c; idx < 32 * 32; idx += 128) {
    int r = idx >> 5;
    float4 v;
    if (r0 + r < n) v = A4[(size_t)(r0 + r) * 32 + (idx & 31)];
    else { v.x = v.y = v.z = v.w = 0.f; }
    a_lds[idx] = v;
  }
  __syncthreads();

  int rmax = n - r0; if (rmax > 32) rmax = 32;
  for (int r = 0; r < rmax; r++) {
    const float4* arow = &a_lds[r * 32];
    float acc0 = 0.f, acc1 = 0.f, acc2 = 0.f, acc3 = 0.f;
#pragma unroll
    for (int k4 = 0; k4 < 32; k4 += 4) {
      float4 a0 = arow[k4 + 0];
      float4 a1 = arow[k4 + 1];
      float4 a2 = arow[k4 + 2];
      float4 a3 = arow[k4 + 3];
      int kb = k4 * 4;
      acc0 += a0.x * w[kb + 0]  + a0.y * w[kb + 1]  + a0.z * w[kb + 2]  + a0.w * w[kb + 3];
      acc1 += a1.x * w[kb + 4]  + a1.y * w[kb + 5]  + a1.z * w[kb + 6]  + a1.w * w[kb + 7];
      acc2 += a2.x * w[kb + 8]  + a2.y * w[kb + 9]  + a2.z * w[kb + 10] + a2.w * w[kb + 11];
      acc3 += a3.x * w[kb + 12] + a3.y * w[kb + 13] + a3.z * w[kb + 14] + a3.w * w[kb + 15];
    }
    C[(size_t)(r0 + r) * 128 + c] = acc0 + acc1 + acc2 + acc3;
  }
}

// ---------------------------------------------------------------------------
// g[node][:] = relu(bias + sum_{e in CSR[node]} w_e * support[src_e][:])
// thread = (node, 4-dim group); float4 gather, no atomics.
__global__ void aggregate(const float* __restrict__ support, const int* __restrict__ row_ptr,
                          const int* __restrict__ csr_src, const float* __restrict__ csr_w,
                          const float* __restrict__ bias, float* __restrict__ out, int n) {
  int gid = blockIdx.x * blockDim.x + threadIdx.x;
  int node = gid >> 5, q = gid & 31;
  if (node >= n) return;
  int beg = row_ptr[node], end = row_ptr[node + 1];
  float4 acc; acc.x = acc.y = acc.z = acc.w = 0.f;
  const float4* s4 = (const float4*)support;
  for (int i = beg; i < end; i++) {
    int s = csr_src[i];
    float wt = csr_w[i];
    float4 v = s4[(size_t)s * 32 + q];
    acc.x += wt * v.x; acc.y += wt * v.y; acc.z += wt * v.z; acc.w += wt * v.w;
  }
  float4 b = ((const float4*)bias)[q];
  acc.x = fmaxf(acc.x + b.x, 0.f);
  acc.y = fmaxf(acc.y + b.y, 0.f);
  acc.z = fmaxf(acc.z + b.z, 0.f);
  acc.w = fmaxf(acc.w + b.w, 0.f);
  ((float4*)out)[(size_t)node * 32 + q] = acc;
}

// ---------------------------------------------------------------------------
// s_pre[n] = h[n] . wa  with h = concat(g1,g2,g3). One wave per node.
__global__ void att_score(const float* __restrict__ g1, const float* __restrict__ g2,
                          const float* __restrict__ g3, const float* __restrict__ wa,
                          float* __restrict__ s_pre, int n) {
  int wid = (blockIdx.x * blockDim.x + threadIdx.x) >> 6;
  int lane = threadIdx.x & 63;
  if (wid >= n) return;
  size_t base = (size_t)wid * 128;
  float acc = g1[base + lane] * wa[lane]       + g1[base + lane + 64] * wa[lane + 64]
            + g2[base + lane] * wa[128 + lane] + g2[base + lane + 64] * wa[192 + lane]
            + g3[base + lane] * wa[256 + lane] + g3[base + lane + 64] * wa[320 + lane];
#pragma unroll
  for (int off = 32; off > 0; off >>= 1) acc += __shfl_down(acc, (unsigned)off, 64);
  if (lane == 0) s_pre[wid] = acc;
}

// ---------------------------------------------------------------------------
// score[n] = tanh(ba + sum_e w_e * s_pre[src_e]). One thread per node.
__global__ void att_aggregate(const float* __restrict__ s_pre, const int* __restrict__ row_ptr,
                              const int* __restrict__ csr_src, const float* __restrict__ csr_w,
                              const float* __restrict__ ba, float* __restrict__ score, int n) {
  int node = blockIdx.x * blockDim.x + threadIdx.x;
  if (node >= n) return;
  int beg = row_ptr[node], end = row_ptr[node + 1];
  float acc = 0.f;
  for (int i = beg; i < end; i++) acc += csr_w[i] * s_pre[csr_src[i]];
  score[node] = tanhf(acc + ba[0]);
}

// ---------------------------------------------------------------------------
// Per-graph node ranges via binary search on sorted graph_indicator.
__global__ void graph_bounds(const void* __restrict__ gi_raw, const int* __restrict__ flags,
                             int* __restrict__ gstart, int n, int ngraphs) {
  int g = threadIdx.x;
  if (g > ngraphs) return;
  if (g == ngraphs) { gstart[g] = n; return; }
  bool is64 = flags[1] != 0;
  const long long* g64 = (const long long*)gi_raw;
  const int* g32 = (const int*)gi_raw;
  int lo = 0, hi = n;
  while (lo < hi) {
    int mid = (lo + hi) >> 1;
    long long v = is64 ? g64[mid] : (long long)g32[mid];
    if (v < (long long)g) lo = mid + 1; else hi = mid;
  }
  gstart[g] = lo;
}

// ---------------------------------------------------------------------------
// Pooling phase 1: grid = G * POOL_SEG blocks; each block reduces a node chunk
// of one graph for all 384 dims into partial sum/max buffers.
__global__ __launch_bounds__(384) void pool_partial(const float* __restrict__ g1,
                                                    const float* __restrict__ g2,
                                                    const float* __restrict__ g3,
                                                    const float* __restrict__ score,
                                                    const int* __restrict__ gstart,
                                                    float* __restrict__ part) {
  int g = blockIdx.x / POOL_SEG, seg = blockIdx.x % POOL_SEG;
  int d = threadIdx.x;           // 0..383
  int sg = d >> 7, dd = d & 127;
  const float* gp = (sg == 0) ? g1 : ((sg == 1) ? g2 : g3);
  int s = gstart[g], e = gstart[g + 1];
  int len = e - s;
  int chunk = (len + POOL_SEG - 1) / POOL_SEG;
  int ns = s + seg * chunk;
  int ne = ns + chunk; if (ne > e) ne = e;
  float sum = 0.f, mx = -3.402823466e38f;
  for (int node = ns; node < ne; node++) {
    float sc = score[node];
    float v = gp[(size_t)node * 128 + dd] * sc;
    sum += v;
    mx = fmaxf(mx, v);
  }
  size_t base = (size_t)blockIdx.x * 768;
  part[base + d] = sum;
  part[base + 384 + d] = mx;
}

// Pooling phase 2: combine POOL_SEG partials per graph; write [avg | max].
__global__ __launch_bounds__(384) void pool_combine(const float* __restrict__ part,
                                                    const int* __restrict__ gstart,
                                                    float* __restrict__ pooled) {
  int g = blockIdx.x;
  int d = threadIdx.x;
  float sum = 0.f, mx = -3.402823466e38f;
  for (int seg = 0; seg < POOL_SEG; seg++) {
    size_t base = ((size_t)g * POOL_SEG + seg) * 768;
    sum += part[base + d];
    mx = fmaxf(mx, part[base + 384 + d]);
  }
  float cnt = (float)(gstart[g + 1] - gstart[g]);
  pooled[(size_t)g * 768 + d] = sum / fmaxf(cnt, 1.0f);
  pooled[(size_t)g * 768 + 384 + d] = mx;
}

// ---------------------------------------------------------------------------
// out = relu(pooled @ Wf + bf).  [64,768]@[768,128]; one block per graph row.
__global__ __launch_bounds__(128) void final_gemm(const float* __restrict__ pooled,
                                                  const float* __restrict__ Wf,
                                                  const float* __restrict__ bf,
                                                  float* __restrict__ out) {
  int g = blockIdx.x;
  int c = threadIdx.x;
  __shared__ float row[768];
  for (int i = c; i < 768; i += 128) row[i] = pooled[(size_t)g * 768 + i];
  __syncthreads();
  float acc = bf[c];
#pragma unroll 8
  for (int k = 0; k < 768; k++) acc += row[k] * Wf[k * 128 + c];
  out[(size_t)g * 128 + c] = fmaxf(acc, 0.f);
}

// ---------------------------------------------------------------------------
extern "C" void kernel_launch(void* const* d_in, const int* in_sizes, int n_in,
                              void* d_out, int out_size, void* d_ws, size_t ws_size,
                              hipStream_t stream) {
  const void* ei_raw = d_in[0];
  const float* ew    = (const float*)d_in[1];
  const float* X     = (const float*)d_in[2];
  const void* gi_raw = d_in[3];
  const float* W1 = (const float*)d_in[4];  const float* b1 = (const float*)d_in[5];
  const float* W2 = (const float*)d_in[6];  const float* b2 = (const float*)d_in[7];
  const float* W3 = (const float*)d_in[8];  const float* b3 = (const float*)d_in[9];
  const float* wa = (const float*)d_in[10]; const float* ba = (const float*)d_in[11];
  const float* Wf = (const float*)d_in[12]; const float* bf = (const float*)d_in[13];
  float* out = (float*)d_out;

  const int E = in_sizes[1];            // 800000
  const int N = in_sizes[2] / 128;      // 50000
  const int G = out_size / 128;         // 64
  const int SB = (N + SCAN_ELEMS - 1) / SCAN_ELEMS;   // scan blocks (13)

  char* ws = (char*)d_ws;
  size_t off = 0;
  auto take = [&](size_t bytes) {
    char* p = ws + off;
    off = (off + bytes + 255) & ~(size_t)255;
    return p;
  };
  int*   flags   = (int*)take(16);
  int*   srcA    = (int*)take((size_t)E * 4);
  int*   dstA    = (int*)take((size_t)E * 4);
  int*   counts  = (int*)take((size_t)N * 4);
  int*   row_ptr = (int*)take((size_t)(N + 1) * 4);
  int*   cursor  = (int*)take((size_t)N * 4);
  int*   partials= (int*)take((size_t)(SB + 1) * 4);
  int*   csr_src = (int*)take((size_t)E * 4);
  float* csr_w   = (float*)take((size_t)E * 4);
  float* support = (float*)take((size_t)N * 128 * 4);
  float* g1      = (float*)take((size_t)N * 128 * 4);
  float* g2      = (float*)take((size_t)N * 128 * 4);
  float* g3      = (float*)take((size_t)N * 128 * 4);
  float* s_pre   = (float*)take((size_t)N * 4);
  float* score   = (float*)take((size_t)N * 4);
  int*   gstart  = (int*)take((size_t)(G + 1) * 4);
  float* part    = (float*)take((size_t)G * POOL_SEG * 768 * 4);
  float* pooled  = (float*)take((size_t)G * 768 * 4);
  if (off > ws_size) return;  // fail loudly (output stays zeroed) rather than corrupt

  hipMemsetAsync(counts, 0, (size_t)N * 4, stream);
  detect_flags<<<1, 64, 0, stream>>>((const int*)ei_raw, (const int*)gi_raw, flags, N);
  load_edges_hist<<<(E + 255) / 256, 256, 0, stream>>>(ei_raw, flags, srcA, dstA, counts, E);
  scan_partial<<<SB, SCAN_TPB, 0, stream>>>(counts, row_ptr, partials, N);
  scan_tops<<<1, 64, 0, stream>>>(partials, SB);
  scan_add<<<(N + 255) / 256, 256, 0, stream>>>(row_ptr, cursor, partials, N, SB);
  scatter_edges<<<(E + 255) / 256, 256, 0, stream>>>(srcA, dstA, ew, cursor, csr_src, csr_w, E);

  // layer 1
  gemm128<<<(N + 31) / 32, 128, 0, stream>>>(X, W1, support, N);
  aggregate<<<((size_t)N * 32 + 255) / 256, 256, 0, stream>>>(support, row_ptr, csr_src, csr_w, b1, g1, N);
  // layer 2
  gemm128<<<(N + 31) / 32, 128, 0, stream>>>(g1, W2, support, N);
  aggregate<<<((size_t)N * 32 + 255) / 256, 256, 0, stream>>>(support, row_ptr, csr_src, csr_w, b2, g2, N);
  // layer 3
  gemm128<<<(N + 31) / 32, 128, 0, stream>>>(g2, W3, support, N);
  aggregate<<<((size_t)N * 32 + 255) / 256, 256, 0, stream>>>(support, row_ptr, csr_src, csr_w, b3, g3, N);

  // attention score
  att_score<<<(N + 3) / 4, 256, 0, stream>>>(g1, g2, g3, wa, s_pre, N);
  att_aggregate<<<(N + 255) / 256, 256, 0, stream>>>(s_pre, row_ptr, csr_src, csr_w, ba, score, N);

  // pooling + readout
  graph_bounds<<<1, 128, 0, stream>>>(gi_raw, flags, gstart, N, G);
  pool_partial<<<G * POOL_SEG, 384, 0, stream>>>(g1, g2, g3, score, gstart, part);
  pool_combine<<<G, 384, 0, stream>>>(part, gstart, pooled);
  final_gemm<<<G, 128, 0, stream>>>(pooled, Wf, bf, out);
}

// Round 3
// 522.459 us; speedup vs baseline: 2.0360x; 1.5298x over previous
//
#include <hip/hip_runtime.h>
#include <math.h>

#define HID 128
#define POOL_SEG 16
#define SCAN_TPB 1024
#define SCAN_ELEMS 4096   // SCAN_TPB * 4
#define WT_STRIDE 136     // padded k-stride (shorts) for transposed bf16 W

typedef __attribute__((ext_vector_type(8))) short short8;   // 8 bf16 = 4 VGPRs
typedef __attribute__((ext_vector_type(4))) float float4v;  // 4 fp32 acc

__device__ inline short f2bf(float f) {
  unsigned u = __builtin_bit_cast(unsigned, f);
  unsigned r = (u + 0x7fff + ((u >> 16) & 1)) >> 16;   // RNE
  return (short)r;
}

// ---------------------------------------------------------------------------
// dtype detection: reference declares int64 indices, harness doc says int32.
__global__ void detect_flags(const int* __restrict__ ei, const int* __restrict__ gi,
                             int* __restrict__ flags, int n_nodes) {
  if (blockIdx.x == 0 && threadIdx.x == 0) {
    int nz = 0;
    for (int i = 1; i < 64; i += 2) nz |= ei[i];
    flags[0] = (nz == 0) ? 1 : 0;                       // 1 => edge_index is int64
    flags[1] = (gi[n_nodes - 1] == 0) ? 1 : 0;          // 1 => graph_indicator is int64
  }
}

// ---------------------------------------------------------------------------
__global__ void load_edges_hist(const void* __restrict__ ei_raw, const int* __restrict__ flags,
                                int* __restrict__ src, int* __restrict__ dst,
                                int* __restrict__ counts, int E) {
  int e = blockIdx.x * blockDim.x + threadIdx.x;
  if (e >= E) return;
  int s, d;
  if (flags[0]) {
    const long long* p = (const long long*)ei_raw;
    s = (int)p[e]; d = (int)p[E + e];
  } else {
    const int* p = (const int*)ei_raw;
    s = p[e]; d = p[E + e];
  }
  src[e] = s; dst[e] = d;
  atomicAdd(&counts[d], 1);
}

// ---------------------------------------------------------------------------
// 3-phase exclusive scan of counts[n] -> row_ptr[0..n], cursor[n].
__global__ __launch_bounds__(SCAN_TPB) void scan_partial(const int* __restrict__ counts,
                                                         int* __restrict__ row_ptr,
                                                         int* __restrict__ partials, int n) {
  __shared__ int wsum[16];
  int b = blockIdx.x, t = threadIdx.x;
  int base = b * SCAN_ELEMS + t * 4;
  int4 v; v.x = v.y = v.z = v.w = 0;
  if (base + 3 < n) v = *(const int4*)(counts + base);
  else {
    if (base + 0 < n) v.x = counts[base + 0];
    if (base + 1 < n) v.y = counts[base + 1];
    if (base + 2 < n) v.z = counts[base + 2];
  }
  int s01 = v.x + v.y, s012 = s01 + v.z, tot4 = s012 + v.w;
  int lane = t & 63, w = t >> 6;
  int incl = tot4;
#pragma unroll
  for (int d = 1; d < 64; d <<= 1) {
    int x = __shfl_up(incl, (unsigned)d, 64);
    if (lane >= d) incl += x;
  }
  if (lane == 63) wsum[w] = incl;
  __syncthreads();
  int wbase = 0;
  for (int j = 0; j < w; j++) wbase += wsum[j];
  int excl = wbase + incl - tot4;
  int4 o; o.x = excl; o.y = excl + v.x; o.z = excl + s01; o.w = excl + s012;
  if (base + 3 < n) *(int4*)(row_ptr + base) = o;
  else {
    if (base + 0 < n) row_ptr[base + 0] = o.x;
    if (base + 1 < n) row_ptr[base + 1] = o.y;
    if (base + 2 < n) row_ptr[base + 2] = o.z;
  }
  if (t == SCAN_TPB - 1) partials[b] = excl + tot4;
}

__global__ void scan_tops(int* __restrict__ partials, int B) {
  int t = threadIdx.x;
  int v = (t < B) ? partials[t] : 0;
  int incl = v;
#pragma unroll
  for (int d = 1; d < 64; d <<= 1) {
    int x = __shfl_up(incl, (unsigned)d, 64);
    if (t >= d) incl += x;
  }
  if (t < B) partials[t] = incl - v;
  if (t == 63) partials[B] = incl;
}

__global__ void scan_add(int* __restrict__ row_ptr, int* __restrict__ cursor,
                         const int* __restrict__ partials, int n, int B) {
  int i = blockIdx.x * blockDim.x + threadIdx.x;
  if (i < n) {
    int v = row_ptr[i] + partials[i >> 12];
    row_ptr[i] = v;
    cursor[i] = v;
  }
  if (i == 0) row_ptr[n] = partials[B];
}

// ---------------------------------------------------------------------------
__global__ void scatter_edges(const int* __restrict__ src, const int* __restrict__ dst,
                              const float* __restrict__ ew, int* __restrict__ cursor,
                              int* __restrict__ csr_src, float* __restrict__ csr_w, int E) {
  int e = blockIdx.x * blockDim.x + threadIdx.x;
  if (e >= E) return;
  int d = dst[e];
  int pos = atomicAdd(&cursor[d], 1);
  csr_src[pos] = src[e];
  csr_w[pos] = ew[e];
}

// ---------------------------------------------------------------------------
// Convert W1/W2/W3 [128k x 128n] fp32 -> transposed padded bf16 Wt[n][k] once.
__global__ void convert_w(const float* __restrict__ W1, const float* __restrict__ W2,
                          const float* __restrict__ W3, short* __restrict__ T1,
                          short* __restrict__ T2, short* __restrict__ T3) {
  int i = blockIdx.x * blockDim.x + threadIdx.x;   // 0 .. 3*16384-1
  int which = i >> 14, idx = i & 16383;
  int k = idx >> 7, n = idx & 127;
  const float* W = (which == 0) ? W1 : ((which == 1) ? W2 : W3);
  short* T = (which == 0) ? T1 : ((which == 1) ? T2 : T3);
  T[n * WT_STRIDE + k] = f2bf(W[idx]);
}

// ---------------------------------------------------------------------------
// C[n x 128] = A[n x 128] @ W[128 x 128] via bf16 MFMA (fp32 accumulate).
// 256 threads = 4 waves; block tile 64 rows; each wave: 16 rows x 128 cols.
// Wt (bf16, [n][k] padded) staged into LDS by plain conflict-free memcpy.
__global__ __launch_bounds__(256) void gemm_mfma(const float* __restrict__ A,
                                                 const short* __restrict__ Wt,
                                                 float* __restrict__ C, int n) {
  __shared__ short Wlds[128 * WT_STRIDE];
  int t = threadIdx.x;
  // stage Wt -> LDS: 128*136 shorts = 2176 x 16B chunks, coalesced, conflict-free
  {
    const ulonglong2* gsrc = (const ulonglong2*)Wt;
    ulonglong2* ldst = (ulonglong2*)Wlds;
    for (int i = t; i < (128 * WT_STRIDE) / 8; i += 256) ldst[i] = gsrc[i];
  }
  __syncthreads();

  int wave = t >> 6, lane = t & 63;
  int quad = lane >> 4, l15 = lane & 15;
  int m0 = blockIdx.x * 64 + wave * 16;

  // A fragments: rows m0..m0+15, fp32 -> bf16. lane holds A[m][c*32+quad*8 ..+7]
  int m = m0 + l15; if (m >= n) m = n - 1;
  const float* Arow = A + (size_t)m * 128;
  short8 afrag[4];
#pragma unroll
  for (int c = 0; c < 4; c++) {
    int k0 = c * 32 + quad * 8;
    float4 x = *(const float4*)(Arow + k0);
    float4 y = *(const float4*)(Arow + k0 + 4);
    short8 a;
    a[0] = f2bf(x.x); a[1] = f2bf(x.y); a[2] = f2bf(x.z); a[3] = f2bf(x.w);
    a[4] = f2bf(y.x); a[5] = f2bf(y.y); a[6] = f2bf(y.z); a[7] = f2bf(y.w);
    afrag[c] = a;
  }

  float4v acc[8];
#pragma unroll
  for (int tt = 0; tt < 8; tt++) acc[tt] = (float4v){0.f, 0.f, 0.f, 0.f};

#pragma unroll
  for (int c = 0; c < 4; c++) {
    int kb = c * 32 + quad * 8;
#pragma unroll
    for (int tt = 0; tt < 8; tt++) {
      const short8* bp = (const short8*)&Wlds[(tt * 16 + l15) * WT_STRIDE + kb];
      acc[tt] = __builtin_amdgcn_mfma_f32_16x16x32_bf16(afrag[c], *bp, acc[tt], 0, 0, 0);
    }
  }

  // C/D layout: col = lane&15, row = quad*4 + reg
  int rbase = m0 + quad * 4;
#pragma unroll
  for (int tt = 0; tt < 8; tt++) {
    int col = tt * 16 + l15;
#pragma unroll
    for (int r = 0; r < 4; r++) {
      int row = rbase + r;
      if (row < n) C[(size_t)row * 128 + col] = acc[tt][r];
    }
  }
}

// ---------------------------------------------------------------------------
// g[node][:] = relu(bias + sum_{e in CSR[node]} w_e * support[src_e][:])
__global__ void aggregate(const float* __restrict__ support, const int* __restrict__ row_ptr,
                          const int* __restrict__ csr_src, const float* __restrict__ csr_w,
                          const float* __restrict__ bias, float* __restrict__ out, int n) {
  int gid = blockIdx.x * blockDim.x + threadIdx.x;
  int node = gid >> 5, q = gid & 31;
  if (node >= n) return;
  int beg = row_ptr[node], end = row_ptr[node + 1];
  float4 acc; acc.x = acc.y = acc.z = acc.w = 0.f;
  const float4* s4 = (const float4*)support;
  for (int i = beg; i < end; i++) {
    int s = csr_src[i];
    float wt = csr_w[i];
    float4 v = s4[(size_t)s * 32 + q];
    acc.x += wt * v.x; acc.y += wt * v.y; acc.z += wt * v.z; acc.w += wt * v.w;
  }
  float4 b = ((const float4*)bias)[q];
  acc.x = fmaxf(acc.x + b.x, 0.f);
  acc.y = fmaxf(acc.y + b.y, 0.f);
  acc.z = fmaxf(acc.z + b.z, 0.f);
  acc.w = fmaxf(acc.w + b.w, 0.f);
  ((float4*)out)[(size_t)node * 32 + q] = acc;
}

// ---------------------------------------------------------------------------
__global__ void att_score(const float* __restrict__ g1, const float* __restrict__ g2,
                          const float* __restrict__ g3, const float* __restrict__ wa,
                          float* __restrict__ s_pre, int n) {
  int wid = (blockIdx.x * blockDim.x + threadIdx.x) >> 6;
  int lane = threadIdx.x & 63;
  if (wid >= n) return;
  size_t base = (size_t)wid * 128;
  float acc = g1[base + lane] * wa[lane]       + g1[base + lane + 64] * wa[lane + 64]
            + g2[base + lane] * wa[128 + lane] + g2[base + lane + 64] * wa[192 + lane]
            + g3[base + lane] * wa[256 + lane] + g3[base + lane + 64] * wa[320 + lane];
#pragma unroll
  for (int off = 32; off > 0; off >>= 1) acc += __shfl_down(acc, (unsigned)off, 64);
  if (lane == 0) s_pre[wid] = acc;
}

// ---------------------------------------------------------------------------
__global__ void att_aggregate(const float* __restrict__ s_pre, const int* __restrict__ row_ptr,
                              const int* __restrict__ csr_src, const float* __restrict__ csr_w,
                              const float* __restrict__ ba, float* __restrict__ score, int n) {
  int node = blockIdx.x * blockDim.x + threadIdx.x;
  if (node >= n) return;
  int beg = row_ptr[node], end = row_ptr[node + 1];
  float acc = 0.f;
  for (int i = beg; i < end; i++) acc += csr_w[i] * s_pre[csr_src[i]];
  score[node] = tanhf(acc + ba[0]);
}

// ---------------------------------------------------------------------------
__global__ void graph_bounds(const void* __restrict__ gi_raw, const int* __restrict__ flags,
                             int* __restrict__ gstart, int n, int ngraphs) {
  int g = threadIdx.x;
  if (g > ngraphs) return;
  if (g == ngraphs) { gstart[g] = n; return; }
  bool is64 = flags[1] != 0;
  const long long* g64 = (const long long*)gi_raw;
  const int* g32 = (const int*)gi_raw;
  int lo = 0, hi = n;
  while (lo < hi) {
    int mid = (lo + hi) >> 1;
    long long v = is64 ? g64[mid] : (long long)g32[mid];
    if (v < (long long)g) lo = mid + 1; else hi = mid;
  }
  gstart[g] = lo;
}

// ---------------------------------------------------------------------------
__global__ __launch_bounds__(384) void pool_partial(const float* __restrict__ g1,
                                                    const float* __restrict__ g2,
                                                    const float* __restrict__ g3,
                                                    const float* __restrict__ score,
                                                    const int* __restrict__ gstart,
                                                    float* __restrict__ part) {
  int g = blockIdx.x / POOL_SEG, seg = blockIdx.x % POOL_SEG;
  int d = threadIdx.x;
  int sg = d >> 7, dd = d & 127;
  const float* gp = (sg == 0) ? g1 : ((sg == 1) ? g2 : g3);
  int s = gstart[g], e = gstart[g + 1];
  int len = e - s;
  int chunk = (len + POOL_SEG - 1) / POOL_SEG;
  int ns = s + seg * chunk;
  int ne = ns + chunk; if (ne > e) ne = e;
  float sum = 0.f, mx = -3.402823466e38f;
  for (int node = ns; node < ne; node++) {
    float sc = score[node];
    float v = gp[(size_t)node * 128 + dd] * sc;
    sum += v;
    mx = fmaxf(mx, v);
  }
  size_t base = (size_t)blockIdx.x * 768;
  part[base + d] = sum;
  part[base + 384 + d] = mx;
}

__global__ __launch_bounds__(384) void pool_combine(const float* __restrict__ part,
                                                    const int* __restrict__ gstart,
                                                    float* __restrict__ pooled) {
  int g = blockIdx.x;
  int d = threadIdx.x;
  float sum = 0.f, mx = -3.402823466e38f;
  for (int seg = 0; seg < POOL_SEG; seg++) {
    size_t base = ((size_t)g * POOL_SEG + seg) * 768;
    sum += part[base + d];
    mx = fmaxf(mx, part[base + 384 + d]);
  }
  float cnt = (float)(gstart[g + 1] - gstart[g]);
  pooled[(size_t)g * 768 + d] = sum / fmaxf(cnt, 1.0f);
  pooled[(size_t)g * 768 + 384 + d] = mx;
}

// ---------------------------------------------------------------------------
__global__ __launch_bounds__(128) void final_gemm(const float* __restrict__ pooled,
                                                  const float* __restrict__ Wf,
                                                  const float* __restrict__ bf,
                                                  float* __restrict__ out) {
  int g = blockIdx.x;
  int c = threadIdx.x;
  __shared__ float row[768];
  for (int i = c; i < 768; i += 128) row[i] = pooled[(size_t)g * 768 + i];
  __syncthreads();
  float acc = bf[c];
#pragma unroll 8
  for (int k = 0; k < 768; k++) acc += row[k] * Wf[k * 128 + c];
  out[(size_t)g * 128 + c] = fmaxf(acc, 0.f);
}

// ---------------------------------------------------------------------------
extern "C" void kernel_launch(void* const* d_in, const int* in_sizes, int n_in,
                              void* d_out, int out_size, void* d_ws, size_t ws_size,
                              hipStream_t stream) {
  const void* ei_raw = d_in[0];
  const float* ew    = (const float*)d_in[1];
  const float* X     = (const float*)d_in[2];
  const void* gi_raw = d_in[3];
  const float* W1 = (const float*)d_in[4];  const float* b1 = (const float*)d_in[5];
  const float* W2 = (const float*)d_in[6];  const float* b2 = (const float*)d_in[7];
  const float* W3 = (const float*)d_in[8];  const float* b3 = (const float*)d_in[9];
  const float* wa = (const float*)d_in[10]; const float* ba = (const float*)d_in[11];
  const float* Wf = (const float*)d_in[12]; const float* bf = (const float*)d_in[13];
  float* out = (float*)d_out;

  const int E = in_sizes[1];            // 800000
  const int N = in_sizes[2] / 128;      // 50000
  const int G = out_size / 128;         // 64
  const int SB = (N + SCAN_ELEMS - 1) / SCAN_ELEMS;

  char* ws = (char*)d_ws;
  size_t off = 0;
  auto take = [&](size_t bytes) {
    char* p = ws + off;
    off = (off + bytes + 255) & ~(size_t)255;
    return p;
  };
  int*   flags   = (int*)take(16);
  int*   srcA    = (int*)take((size_t)E * 4);
  int*   dstA    = (int*)take((size_t)E * 4);
  int*   counts  = (int*)take((size_t)N * 4);
  int*   row_ptr = (int*)take((size_t)(N + 1) * 4);
  int*   cursor  = (int*)take((size_t)N * 4);
  int*   partials= (int*)take((size_t)(SB + 1) * 4);
  int*   csr_src = (int*)take((size_t)E * 4);
  float* csr_w   = (float*)take((size_t)E * 4);
  short* wt1     = (short*)take((size_t)128 * WT_STRIDE * 2);
  short* wt2     = (short*)take((size_t)128 * WT_STRIDE * 2);
  short* wt3     = (short*)take((size_t)128 * WT_STRIDE * 2);
  float* support = (float*)take((size_t)N * 128 * 4);
  float* g1      = (float*)take((size_t)N * 128 * 4);
  float* g2      = (float*)take((size_t)N * 128 * 4);
  float* g3      = (float*)take((size_t)N * 128 * 4);
  float* s_pre   = (float*)take((size_t)N * 4);
  float* score   = (float*)take((size_t)N * 4);
  int*   gstart  = (int*)take((size_t)(G + 1) * 4);
  float* part    = (float*)take((size_t)G * POOL_SEG * 768 * 4);
  float* pooled  = (float*)take((size_t)G * 768 * 4);
  if (off > ws_size) return;

  hipMemsetAsync(counts, 0, (size_t)N * 4, stream);
  detect_flags<<<1, 64, 0, stream>>>((const int*)ei_raw, (const int*)gi_raw, flags, N);
  load_edges_hist<<<(E + 255) / 256, 256, 0, stream>>>(ei_raw, flags, srcA, dstA, counts, E);
  scan_partial<<<SB, SCAN_TPB, 0, stream>>>(counts, row_ptr, partials, N);
  scan_tops<<<1, 64, 0, stream>>>(partials, SB);
  scan_add<<<(N + 255) / 256, 256, 0, stream>>>(row_ptr, cursor, partials, N, SB);
  scatter_edges<<<(E + 255) / 256, 256, 0, stream>>>(srcA, dstA, ew, cursor, csr_src, csr_w, E);
  convert_w<<<(3 * 16384 + 255) / 256, 256, 0, stream>>>(W1, W2, W3, wt1, wt2, wt3);

  const int GB = (N + 63) / 64;   // gemm blocks
  // layer 1
  gemm_mfma<<<GB, 256, 0, stream>>>(X, wt1, support, N);
  aggregate<<<((size_t)N * 32 + 255) / 256, 256, 0, stream>>>(support, row_ptr, csr_src, csr_w, b1, g1, N);
  // layer 2
  gemm_mfma<<<GB, 256, 0, stream>>>(g1, wt2, support, N);
  aggregate<<<((size_t)N * 32 + 255) / 256, 256, 0, stream>>>(support, row_ptr, csr_src, csr_w, b2, g2, N);
  // layer 3
  gemm_mfma<<<GB, 256, 0, stream>>>(g2, wt3, support, N);
  aggregate<<<((size_t)N * 32 + 255) / 256, 256, 0, stream>>>(support, row_ptr, csr_src, csr_w, b3, g3, N);

  // attention
  att_score<<<(N + 3) / 4, 256, 0, stream>>>(g1, g2, g3, wa, s_pre, N);
  att_aggregate<<<(N + 255) / 256, 256, 0, stream>>>(s_pre, row_ptr, csr_src, csr_w, ba, score, N);

  // pooling + readout
  graph_bounds<<<1, 128, 0, stream>>>(gi_raw, flags, gstart, N, G);
  pool_partial<<<G * POOL_SEG, 384, 0, stream>>>(g1, g2, g3, score, gstart, part);
  pool_combine<<<G, 384, 0, stream>>>(part, gstart, pooled);
  final_gemm<<<G, 128, 0, stream>>>(pooled, Wf, bf, out);
}

// Round 4
// 409.510 us; speedup vs baseline: 2.5976x; 1.2758x over previous
//
#include <hip/hip_runtime.h>
#include <math.h>

#define HID 128
#define POOL_SEG 16
#define SCAN_TPB 1024
#define SCAN_ELEMS 4096   // SCAN_TPB * 4
#define WT_STRIDE 136     // padded k-stride (shorts) for transposed bf16 W

typedef __attribute__((ext_vector_type(8))) short short8;   // 8 bf16 = 4 VGPRs
typedef __attribute__((ext_vector_type(4))) float float4v;  // 4 fp32 acc

__device__ inline short f2bf(float f) {
  unsigned u = __builtin_bit_cast(unsigned, f);
  unsigned r = (u + 0x7fff + ((u >> 16) & 1)) >> 16;   // RNE
  return (short)r;
}
__device__ inline unsigned pack2bf(float lo, float hi) {
  return (unsigned)(unsigned short)f2bf(lo) | ((unsigned)(unsigned short)f2bf(hi) << 16);
}
__device__ inline float bflo(unsigned u) { return __builtin_bit_cast(float, u << 16); }
__device__ inline float bfhi(unsigned u) { return __builtin_bit_cast(float, u & 0xffff0000u); }
__device__ inline float bf2f(unsigned short s) { return __builtin_bit_cast(float, (unsigned)s << 16); }

// ---------------------------------------------------------------------------
__global__ void detect_flags(const int* __restrict__ ei, const int* __restrict__ gi,
                             int* __restrict__ flags, int n_nodes) {
  if (blockIdx.x == 0 && threadIdx.x == 0) {
    int nz = 0;
    for (int i = 1; i < 64; i += 2) nz |= ei[i];
    flags[0] = (nz == 0) ? 1 : 0;                       // 1 => edge_index is int64
    flags[1] = (gi[n_nodes - 1] == 0) ? 1 : 0;          // 1 => graph_indicator is int64
  }
}

// ---------------------------------------------------------------------------
__global__ void load_edges_hist(const void* __restrict__ ei_raw, const int* __restrict__ flags,
                                int* __restrict__ src, int* __restrict__ dst,
                                int* __restrict__ counts, int E) {
  int e = blockIdx.x * blockDim.x + threadIdx.x;
  if (e >= E) return;
  int s, d;
  if (flags[0]) {
    const long long* p = (const long long*)ei_raw;
    s = (int)p[e]; d = (int)p[E + e];
  } else {
    const int* p = (const int*)ei_raw;
    s = p[e]; d = p[E + e];
  }
  src[e] = s; dst[e] = d;
  atomicAdd(&counts[d], 1);
}

// ---------------------------------------------------------------------------
__global__ __launch_bounds__(SCAN_TPB) void scan_partial(const int* __restrict__ counts,
                                                         int* __restrict__ row_ptr,
                                                         int* __restrict__ partials, int n) {
  __shared__ int wsum[16];
  int b = blockIdx.x, t = threadIdx.x;
  int base = b * SCAN_ELEMS + t * 4;
  int4 v; v.x = v.y = v.z = v.w = 0;
  if (base + 3 < n) v = *(const int4*)(counts + base);
  else {
    if (base + 0 < n) v.x = counts[base + 0];
    if (base + 1 < n) v.y = counts[base + 1];
    if (base + 2 < n) v.z = counts[base + 2];
  }
  int s01 = v.x + v.y, s012 = s01 + v.z, tot4 = s012 + v.w;
  int lane = t & 63, w = t >> 6;
  int incl = tot4;
#pragma unroll
  for (int d = 1; d < 64; d <<= 1) {
    int x = __shfl_up(incl, (unsigned)d, 64);
    if (lane >= d) incl += x;
  }
  if (lane == 63) wsum[w] = incl;
  __syncthreads();
  int wbase = 0;
  for (int j = 0; j < w; j++) wbase += wsum[j];
  int excl = wbase + incl - tot4;
  int4 o; o.x = excl; o.y = excl + v.x; o.z = excl + s01; o.w = excl + s012;
  if (base + 3 < n) *(int4*)(row_ptr + base) = o;
  else {
    if (base + 0 < n) row_ptr[base + 0] = o.x;
    if (base + 1 < n) row_ptr[base + 1] = o.y;
    if (base + 2 < n) row_ptr[base + 2] = o.z;
  }
  if (t == SCAN_TPB - 1) partials[b] = excl + tot4;
}

__global__ void scan_tops(int* __restrict__ partials, int B) {
  int t = threadIdx.x;
  int v = (t < B) ? partials[t] : 0;
  int incl = v;
#pragma unroll
  for (int d = 1; d < 64; d <<= 1) {
    int x = __shfl_up(incl, (unsigned)d, 64);
    if (t >= d) incl += x;
  }
  if (t < B) partials[t] = incl - v;
  if (t == 63) partials[B] = incl;
}

__global__ void scan_add(int* __restrict__ row_ptr, int* __restrict__ cursor,
                         const int* __restrict__ partials, int n, int B) {
  int i = blockIdx.x * blockDim.x + threadIdx.x;
  if (i < n) {
    int v = row_ptr[i] + partials[i >> 12];
    row_ptr[i] = v;
    cursor[i] = v;
  }
  if (i == 0) row_ptr[n] = partials[B];
}

// ---------------------------------------------------------------------------
__global__ void scatter_edges(const int* __restrict__ src, const int* __restrict__ dst,
                              const float* __restrict__ ew, int* __restrict__ cursor,
                              int* __restrict__ csr_src, float* __restrict__ csr_w, int E) {
  int e = blockIdx.x * blockDim.x + threadIdx.x;
  if (e >= E) return;
  int d = dst[e];
  int pos = atomicAdd(&cursor[d], 1);
  csr_src[pos] = src[e];
  csr_w[pos] = ew[e];
}

// ---------------------------------------------------------------------------
__global__ void convert_w(const float* __restrict__ W1, const float* __restrict__ W2,
                          const float* __restrict__ W3, short* __restrict__ T1,
                          short* __restrict__ T2, short* __restrict__ T3) {
  int i = blockIdx.x * blockDim.x + threadIdx.x;   // 0 .. 3*16384-1
  int which = i >> 14, idx = i & 16383;
  int k = idx >> 7, n = idx & 127;
  const float* W = (which == 0) ? W1 : ((which == 1) ? W2 : W3);
  short* T = (which == 0) ? T1 : ((which == 1) ? T2 : T3);
  T[n * WT_STRIDE + k] = f2bf(W[idx]);
}

// ---------------------------------------------------------------------------
// C[n x 128](bf16) = A[n x 128] @ W[128 x 128] via bf16 MFMA (fp32 accumulate).
// A is fp32 (a_is_bf16=0, layer 1) or bf16 (layers 2,3).
__global__ __launch_bounds__(256) void gemm_mfma(const float* __restrict__ Af,
                                                 const unsigned short* __restrict__ Abf,
                                                 const short* __restrict__ Wt,
                                                 unsigned short* __restrict__ C,
                                                 int n, int a_is_bf16) {
  __shared__ short Wlds[128 * WT_STRIDE];
  int t = threadIdx.x;
  {
    const ulonglong2* gsrc = (const ulonglong2*)Wt;
    ulonglong2* ldst = (ulonglong2*)Wlds;
    for (int i = t; i < (128 * WT_STRIDE) / 8; i += 256) ldst[i] = gsrc[i];
  }
  __syncthreads();

  int wave = t >> 6, lane = t & 63;
  int quad = lane >> 4, l15 = lane & 15;
  int m0 = blockIdx.x * 64 + wave * 16;

  int m = m0 + l15; if (m >= n) m = n - 1;
  short8 afrag[4];
  if (a_is_bf16) {
    const unsigned short* Arow = Abf + (size_t)m * 128;
#pragma unroll
    for (int c = 0; c < 4; c++) afrag[c] = *(const short8*)(Arow + c * 32 + quad * 8);
  } else {
    const float* Arow = Af + (size_t)m * 128;
#pragma unroll
    for (int c = 0; c < 4; c++) {
      int k0 = c * 32 + quad * 8;
      float4 x = *(const float4*)(Arow + k0);
      float4 y = *(const float4*)(Arow + k0 + 4);
      short8 a;
      a[0] = f2bf(x.x); a[1] = f2bf(x.y); a[2] = f2bf(x.z); a[3] = f2bf(x.w);
      a[4] = f2bf(y.x); a[5] = f2bf(y.y); a[6] = f2bf(y.z); a[7] = f2bf(y.w);
      afrag[c] = a;
    }
  }

  float4v acc[8];
#pragma unroll
  for (int tt = 0; tt < 8; tt++) acc[tt] = (float4v){0.f, 0.f, 0.f, 0.f};

#pragma unroll
  for (int c = 0; c < 4; c++) {
    int kb = c * 32 + quad * 8;
#pragma unroll
    for (int tt = 0; tt < 8; tt++) {
      const short8* bp = (const short8*)&Wlds[(tt * 16 + l15) * WT_STRIDE + kb];
      acc[tt] = __builtin_amdgcn_mfma_f32_16x16x32_bf16(afrag[c], *bp, acc[tt], 0, 0, 0);
    }
  }

  // C/D layout: col = lane&15, row = quad*4 + reg
  int rbase = m0 + quad * 4;
#pragma unroll
  for (int tt = 0; tt < 8; tt++) {
    int col = tt * 16 + l15;
#pragma unroll
    for (int r = 0; r < 4; r++) {
      int row = rbase + r;
      if (row < n) C[(size_t)row * 128 + col] = (unsigned short)f2bf(acc[tt][r]);
    }
  }
}

// ---------------------------------------------------------------------------
// g[node][:] = relu(bias + sum_e w_e * support[src_e][:]) — bf16 in/out, fp32 acc.
// 16 lanes per node, each lane covers 8 dims (one uint4 = 8 bf16), 2-edge unroll.
__global__ void aggregate(const unsigned short* __restrict__ support,
                          const int* __restrict__ row_ptr,
                          const int* __restrict__ csr_src, const float* __restrict__ csr_w,
                          const float* __restrict__ bias, unsigned short* __restrict__ out,
                          int n) {
  int gid = blockIdx.x * blockDim.x + threadIdx.x;
  int node = gid >> 4, q = gid & 15;
  if (node >= n) return;
  int beg = row_ptr[node], end = row_ptr[node + 1];
  float acc[8];
#pragma unroll
  for (int j = 0; j < 8; j++) acc[j] = 0.f;
  const uint4* s4 = (const uint4*)support;

  int i = beg;
  for (; i + 1 < end; i += 2) {
    int s0 = csr_src[i], s1 = csr_src[i + 1];
    float w0 = csr_w[i], w1 = csr_w[i + 1];
    uint4 v0 = s4[(size_t)s0 * 16 + q];
    uint4 v1 = s4[(size_t)s1 * 16 + q];
    acc[0] += w0 * bflo(v0.x); acc[1] += w0 * bfhi(v0.x);
    acc[2] += w0 * bflo(v0.y); acc[3] += w0 * bfhi(v0.y);
    acc[4] += w0 * bflo(v0.z); acc[5] += w0 * bfhi(v0.z);
    acc[6] += w0 * bflo(v0.w); acc[7] += w0 * bfhi(v0.w);
    acc[0] += w1 * bflo(v1.x); acc[1] += w1 * bfhi(v1.x);
    acc[2] += w1 * bflo(v1.y); acc[3] += w1 * bfhi(v1.y);
    acc[4] += w1 * bflo(v1.z); acc[5] += w1 * bfhi(v1.z);
    acc[6] += w1 * bflo(v1.w); acc[7] += w1 * bfhi(v1.w);
  }
  if (i < end) {
    int s0 = csr_src[i];
    float w0 = csr_w[i];
    uint4 v0 = s4[(size_t)s0 * 16 + q];
    acc[0] += w0 * bflo(v0.x); acc[1] += w0 * bfhi(v0.x);
    acc[2] += w0 * bflo(v0.y); acc[3] += w0 * bfhi(v0.y);
    acc[4] += w0 * bflo(v0.z); acc[5] += w0 * bfhi(v0.z);
    acc[6] += w0 * bflo(v0.w); acc[7] += w0 * bfhi(v0.w);
  }

  float4 b0 = ((const float4*)bias)[q * 2];
  float4 b1 = ((const float4*)bias)[q * 2 + 1];
  acc[0] = fmaxf(acc[0] + b0.x, 0.f); acc[1] = fmaxf(acc[1] + b0.y, 0.f);
  acc[2] = fmaxf(acc[2] + b0.z, 0.f); acc[3] = fmaxf(acc[3] + b0.w, 0.f);
  acc[4] = fmaxf(acc[4] + b1.x, 0.f); acc[5] = fmaxf(acc[5] + b1.y, 0.f);
  acc[6] = fmaxf(acc[6] + b1.z, 0.f); acc[7] = fmaxf(acc[7] + b1.w, 0.f);

  uint4 o;
  o.x = pack2bf(acc[0], acc[1]); o.y = pack2bf(acc[2], acc[3]);
  o.z = pack2bf(acc[4], acc[5]); o.w = pack2bf(acc[6], acc[7]);
  ((uint4*)out)[(size_t)node * 16 + q] = o;
}

// ---------------------------------------------------------------------------
// s_pre[n] = h[n] . wa, h = concat(g1,g2,g3) bf16. One wave per node; lane
// covers dims 2*lane, 2*lane+1 of each g.
__global__ void att_score(const unsigned short* __restrict__ g1,
                          const unsigned short* __restrict__ g2,
                          const unsigned short* __restrict__ g3,
                          const float* __restrict__ wa,
                          float* __restrict__ s_pre, int n) {
  int wid = (blockIdx.x * blockDim.x + threadIdx.x) >> 6;
  int lane = threadIdx.x & 63;
  if (wid >= n) return;
  size_t base = (size_t)wid * 64;   // in uints
  unsigned u1 = ((const unsigned*)g1)[base + lane];
  unsigned u2 = ((const unsigned*)g2)[base + lane];
  unsigned u3 = ((const unsigned*)g3)[base + lane];
  int d0 = 2 * lane;
  float acc = bflo(u1) * wa[d0]       + bfhi(u1) * wa[d0 + 1]
            + bflo(u2) * wa[128 + d0] + bfhi(u2) * wa[128 + d0 + 1]
            + bflo(u3) * wa[256 + d0] + bfhi(u3) * wa[256 + d0 + 1];
#pragma unroll
  for (int off = 32; off > 0; off >>= 1) acc += __shfl_down(acc, (unsigned)off, 64);
  if (lane == 0) s_pre[wid] = acc;
}

// ---------------------------------------------------------------------------
__global__ void att_aggregate(const float* __restrict__ s_pre, const int* __restrict__ row_ptr,
                              const int* __restrict__ csr_src, const float* __restrict__ csr_w,
                              const float* __restrict__ ba, float* __restrict__ score, int n) {
  int node = blockIdx.x * blockDim.x + threadIdx.x;
  if (node >= n) return;
  int beg = row_ptr[node], end = row_ptr[node + 1];
  float acc = 0.f;
  for (int i = beg; i < end; i++) acc += csr_w[i] * s_pre[csr_src[i]];
  score[node] = tanhf(acc + ba[0]);
}

// ---------------------------------------------------------------------------
__global__ void graph_bounds(const void* __restrict__ gi_raw, const int* __restrict__ flags,
                             int* __restrict__ gstart, int n, int ngraphs) {
  int g = threadIdx.x;
  if (g > ngraphs) return;
  if (g == ngraphs) { gstart[g] = n; return; }
  bool is64 = flags[1] != 0;
  const long long* g64 = (const long long*)gi_raw;
  const int* g32 = (const int*)gi_raw;
  int lo = 0, hi = n;
  while (lo < hi) {
    int mid = (lo + hi) >> 1;
    long long v = is64 ? g64[mid] : (long long)g32[mid];
    if (v < (long long)g) lo = mid + 1; else hi = mid;
  }
  gstart[g] = lo;
}

// ---------------------------------------------------------------------------
__global__ __launch_bounds__(384) void pool_partial(const unsigned short* __restrict__ g1,
                                                    const unsigned short* __restrict__ g2,
                                                    const unsigned short* __restrict__ g3,
                                                    const float* __restrict__ score,
                                                    const int* __restrict__ gstart,
                                                    float* __restrict__ part) {
  int g = blockIdx.x / POOL_SEG, seg = blockIdx.x % POOL_SEG;
  int d = threadIdx.x;
  int sg = d >> 7, dd = d & 127;
  const unsigned short* gp = (sg == 0) ? g1 : ((sg == 1) ? g2 : g3);
  int s = gstart[g], e = gstart[g + 1];
  int len = e - s;
  int chunk = (len + POOL_SEG - 1) / POOL_SEG;
  int ns = s + seg * chunk;
  int ne = ns + chunk; if (ne > e) ne = e;
  float sum = 0.f, mx = -3.402823466e38f;
  for (int node = ns; node < ne; node++) {
    float sc = score[node];
    float v = bf2f(gp[(size_t)node * 128 + dd]) * sc;
    sum += v;
    mx = fmaxf(mx, v);
  }
  size_t base = (size_t)blockIdx.x * 768;
  part[base + d] = sum;
  part[base + 384 + d] = mx;
}

__global__ __launch_bounds__(384) void pool_combine(const float* __restrict__ part,
                                                    const int* __restrict__ gstart,
                                                    float* __restrict__ pooled) {
  int g = blockIdx.x;
  int d = threadIdx.x;
  float sum = 0.f, mx = -3.402823466e38f;
  for (int seg = 0; seg < POOL_SEG; seg++) {
    size_t base = ((size_t)g * POOL_SEG + seg) * 768;
    sum += part[base + d];
    mx = fmaxf(mx, part[base + 384 + d]);
  }
  float cnt = (float)(gstart[g + 1] - gstart[g]);
  pooled[(size_t)g * 768 + d] = sum / fmaxf(cnt, 1.0f);
  pooled[(size_t)g * 768 + 384 + d] = mx;
}

// ---------------------------------------------------------------------------
__global__ __launch_bounds__(128) void final_gemm(const float* __restrict__ pooled,
                                                  const float* __restrict__ Wf,
                                                  const float* __restrict__ bf,
                                                  float* __restrict__ out) {
  int g = blockIdx.x;
  int c = threadIdx.x;
  __shared__ float row[768];
  for (int i = c; i < 768; i += 128) row[i] = pooled[(size_t)g * 768 + i];
  __syncthreads();
  float acc = bf[c];
#pragma unroll 8
  for (int k = 0; k < 768; k++) acc += row[k] * Wf[k * 128 + c];
  out[(size_t)g * 128 + c] = fmaxf(acc, 0.f);
}

// ---------------------------------------------------------------------------
extern "C" void kernel_launch(void* const* d_in, const int* in_sizes, int n_in,
                              void* d_out, int out_size, void* d_ws, size_t ws_size,
                              hipStream_t stream) {
  const void* ei_raw = d_in[0];
  const float* ew    = (const float*)d_in[1];
  const float* X     = (const float*)d_in[2];
  const void* gi_raw = d_in[3];
  const float* W1 = (const float*)d_in[4];  const float* b1 = (const float*)d_in[5];
  const float* W2 = (const float*)d_in[6];  const float* b2 = (const float*)d_in[7];
  const float* W3 = (const float*)d_in[8];  const float* b3 = (const float*)d_in[9];
  const float* wa = (const float*)d_in[10]; const float* ba = (const float*)d_in[11];
  const float* Wf = (const float*)d_in[12]; const float* bf = (const float*)d_in[13];
  float* out = (float*)d_out;

  const int E = in_sizes[1];            // 800000
  const int N = in_sizes[2] / 128;      // 50000
  const int G = out_size / 128;         // 64
  const int SB = (N + SCAN_ELEMS - 1) / SCAN_ELEMS;

  char* ws = (char*)d_ws;
  size_t off = 0;
  auto take = [&](size_t bytes) {
    char* p = ws + off;
    off = (off + bytes + 255) & ~(size_t)255;
    return p;
  };
  int*   flags   = (int*)take(16);
  int*   srcA    = (int*)take((size_t)E * 4);
  int*   dstA    = (int*)take((size_t)E * 4);
  int*   counts  = (int*)take((size_t)N * 4);
  int*   row_ptr = (int*)take((size_t)(N + 1) * 4);
  int*   cursor  = (int*)take((size_t)N * 4);
  int*   partials= (int*)take((size_t)(SB + 1) * 4);
  int*   csr_src = (int*)take((size_t)E * 4);
  float* csr_w   = (float*)take((size_t)E * 4);
  short* wt1     = (short*)take((size_t)128 * WT_STRIDE * 2);
  short* wt2     = (short*)take((size_t)128 * WT_STRIDE * 2);
  short* wt3     = (short*)take((size_t)128 * WT_STRIDE * 2);
  unsigned short* support = (unsigned short*)take((size_t)N * 128 * 2);
  unsigned short* g1      = (unsigned short*)take((size_t)N * 128 * 2);
  unsigned short* g2      = (unsigned short*)take((size_t)N * 128 * 2);
  unsigned short* g3      = (unsigned short*)take((size_t)N * 128 * 2);
  float* s_pre   = (float*)take((size_t)N * 4);
  float* score   = (float*)take((size_t)N * 4);
  int*   gstart  = (int*)take((size_t)(G + 1) * 4);
  float* part    = (float*)take((size_t)G * POOL_SEG * 768 * 4);
  float* pooled  = (float*)take((size_t)G * 768 * 4);
  if (off > ws_size) return;

  hipMemsetAsync(counts, 0, (size_t)N * 4, stream);
  detect_flags<<<1, 64, 0, stream>>>((const int*)ei_raw, (const int*)gi_raw, flags, N);
  load_edges_hist<<<(E + 255) / 256, 256, 0, stream>>>(ei_raw, flags, srcA, dstA, counts, E);
  scan_partial<<<SB, SCAN_TPB, 0, stream>>>(counts, row_ptr, partials, N);
  scan_tops<<<1, 64, 0, stream>>>(partials, SB);
  scan_add<<<(N + 255) / 256, 256, 0, stream>>>(row_ptr, cursor, partials, N, SB);
  scatter_edges<<<(E + 255) / 256, 256, 0, stream>>>(srcA, dstA, ew, cursor, csr_src, csr_w, E);
  convert_w<<<(3 * 16384 + 255) / 256, 256, 0, stream>>>(W1, W2, W3, wt1, wt2, wt3);

  const int GB = (N + 63) / 64;
  const int AB = (N * 16 + 255) / 256;
  // layer 1
  gemm_mfma<<<GB, 256, 0, stream>>>(X, (const unsigned short*)nullptr, wt1, support, N, 0);
  aggregate<<<AB, 256, 0, stream>>>(support, row_ptr, csr_src, csr_w, b1, g1, N);
  // layer 2
  gemm_mfma<<<GB, 256, 0, stream>>>((const float*)nullptr, g1, wt2, support, N, 1);
  aggregate<<<AB, 256, 0, stream>>>(support, row_ptr, csr_src, csr_w, b2, g2, N);
  // layer 3
  gemm_mfma<<<GB, 256, 0, stream>>>((const float*)nullptr, g2, wt3, support, N, 1);
  aggregate<<<AB, 256, 0, stream>>>(support, row_ptr, csr_src, csr_w, b3, g3, N);

  // attention
  att_score<<<(N + 3) / 4, 256, 0, stream>>>(g1, g2, g3, wa, s_pre, N);
  att_aggregate<<<(N + 255) / 256, 256, 0, stream>>>(s_pre, row_ptr, csr_src, csr_w, ba, score, N);

  // pooling + readout
  graph_bounds<<<1, 128, 0, stream>>>(gi_raw, flags, gstart, N, G);
  pool_partial<<<G * POOL_SEG, 384, 0, stream>>>(g1, g2, g3, score, gstart, part);
  pool_combine<<<G, 384, 0, stream>>>(part, gstart, pooled);
  final_gemm<<<G, 128, 0, stream>>>(pooled, Wf, bf, out);
}